// Round 1
// baseline (353.311 us; speedup 1.0000x reference)
//
#include <hip/hip_runtime.h>
#include <hip/hip_bf16.h>

// Per-row mode, N=1048576 rows x K=64 cols, values are floats in {0..7}.
// Strategy: 8-bin histogram packed into a single uint64 (8 bits/bin; max
// count 64 fits). Tie-break: smallest value wins (strict > scan from v=0),
// matching torch.mode / the reference's argmax-on-sorted-first-max.

#define K 64

__global__ __launch_bounds__(256) void mode_rows_kernel(
    const float* __restrict__ x, float* __restrict__ out, int n) {
    int row = blockIdx.x * blockDim.x + threadIdx.x;
    if (row >= n) return;

    const float4* p = (const float4*)(x + (size_t)row * K);

    unsigned long long cnt = 0ULL;
    #pragma unroll
    for (int k = 0; k < K / 4; ++k) {
        float4 v = p[k];
        cnt += 1ULL << (((int)v.x) << 3);
        cnt += 1ULL << (((int)v.y) << 3);
        cnt += 1ULL << (((int)v.z) << 3);
        cnt += 1ULL << (((int)v.w) << 3);
    }

    int best_v = 0;
    int best_c = -1;
    #pragma unroll
    for (int v = 0; v < 8; ++v) {
        int c = (int)((cnt >> (v << 3)) & 0xFFULL);
        if (c > best_c) { best_c = c; best_v = v; }
    }

    out[row] = (float)best_v;
}

extern "C" void kernel_launch(void* const* d_in, const int* in_sizes, int n_in,
                              void* d_out, int out_size, void* d_ws, size_t ws_size,
                              hipStream_t stream) {
    const float* x = (const float*)d_in[0];
    float* out = (float*)d_out;
    int n = in_sizes[0] / K;  // number of rows

    const int block = 256;
    const int grid = (n + block - 1) / block;
    mode_rows_kernel<<<grid, block, 0, stream>>>(x, out, n);
}

// Round 2
// 337.133 us; speedup vs baseline: 1.0480x; 1.0480x over previous
//
#include <hip/hip_runtime.h>
#include <hip/hip_bf16.h>

// Per-row mode, N=1048576 rows x K=64 cols, values are floats in {0..7}.
//
// R1 lesson: one-thread-per-row (256B inter-lane stride) ran at 0.74 TB/s
// effective -- every dwordx4 touched 64 distinct cache lines. Fix: 16 lanes
// cooperate on one row so each wave load instruction reads 1 KiB contiguous.
//
// Each lane: load one float4 (4 elems), build packed 8x8-bit histogram in a
// uint64 (max count 64 < 256, no overflow), then 4-step shfl_xor reduction
// (masks 1,2,4,8 stay inside the 16-lane group). Tie-break: strict > scan
// from v=0 gives the smallest value, matching torch.mode / the reference.

#define K 64

__global__ __launch_bounds__(256) void mode_rows_kernel(
    const float* __restrict__ x, float* __restrict__ out, int nrows) {
    int tid = blockIdx.x * blockDim.x + threadIdx.x;
    int row = tid >> 4;        // 16 lanes per row
    int sub = tid & 15;
    if (row >= nrows) return;

    // lane `sub` reads bytes [sub*16, sub*16+16) of the row: fully coalesced
    float4 v = ((const float4*)(x + (size_t)row * K))[sub];

    unsigned long long cnt = 0ULL;
    cnt += 1ULL << (((int)v.x) << 3);
    cnt += 1ULL << (((int)v.y) << 3);
    cnt += 1ULL << (((int)v.z) << 3);
    cnt += 1ULL << (((int)v.w) << 3);

    // sum the 16 partial histograms; masks < 16 never cross the group
    #pragma unroll
    for (int m = 1; m < 16; m <<= 1)
        cnt += (unsigned long long)__shfl_xor((unsigned long long)cnt, m);

    if (sub == 0) {
        int best_v = 0;
        int best_c = -1;
        #pragma unroll
        for (int vbin = 0; vbin < 8; ++vbin) {
            int c = (int)((cnt >> (vbin << 3)) & 0xFFULL);
            if (c > best_c) { best_c = c; best_v = vbin; }
        }
        out[row] = (float)best_v;
    }
}

extern "C" void kernel_launch(void* const* d_in, const int* in_sizes, int n_in,
                              void* d_out, int out_size, void* d_ws, size_t ws_size,
                              hipStream_t stream) {
    const float* x = (const float*)d_in[0];
    float* out = (float*)d_out;
    int nrows = in_sizes[0] / K;

    const int block = 256;                       // 16 rows per block
    const int grid = (nrows * 16 + block - 1) / block;
    mode_rows_kernel<<<grid, block, 0, stream>>>(x, out, nrows);
}